// Round 1
// baseline (642.379 us; speedup 1.0000x reference)
//
#include <hip/hip_runtime.h>

#define M_DIM 8192   // IN_FEATURES (rows of W, rows of out)
#define K_DIM 4096   // OUT_FEATURES (cols of W = reduction dim)
#define N_DIM 4096   // N_COLS
#define NNZ_CNT 4194304

typedef __attribute__((ext_vector_type(8))) short bf16x8;
typedef __attribute__((ext_vector_type(4))) float f32x4;

__device__ __forceinline__ unsigned short f2bf(float f) {
  unsigned int u = __float_as_uint(f);
  unsigned int r = (u + 0x7FFFu + ((u >> 16) & 1u)) >> 16;  // RNE
  return (unsigned short)r;
}

__device__ __forceinline__ void gload_lds16(const void* g, void* l) {
  __builtin_amdgcn_global_load_lds(
      (const __attribute__((address_space(1))) void*)g,
      (__attribute__((address_space(3))) void*)l, 16, 0, 0);
}

__global__ void zero_f32(float* __restrict__ p, long n4) {
  long i = (long)blockIdx.x * blockDim.x + threadIdx.x;
  long stride = (long)gridDim.x * blockDim.x;
  float4 z = {0.f, 0.f, 0.f, 0.f};
  for (; i < n4; i += stride) ((float4*)p)[i] = z;
}

__global__ void scatter_coo(const float* __restrict__ vals,
                            const int* __restrict__ rows,
                            const int* __restrict__ cols,
                            float* __restrict__ W) {
  int i = blockIdx.x * blockDim.x + threadIdx.x;
  int stride = gridDim.x * blockDim.x;
  for (; i < NNZ_CNT; i += stride)
    atomicAdd(&W[(long)rows[i] * K_DIM + cols[i]], vals[i]);
}

__global__ void cvt_f32_bf16(const float4* __restrict__ src,
                             ushort4* __restrict__ dst, long n4) {
  long i = (long)blockIdx.x * blockDim.x + threadIdx.x;
  long stride = (long)gridDim.x * blockDim.x;
  for (; i < n4; i += stride) {
    float4 v = src[i];
    ushort4 o;
    o.x = f2bf(v.x); o.y = f2bf(v.y); o.z = f2bf(v.z); o.w = f2bf(v.w);
    dst[i] = o;
  }
}

// xT[n][k] = bf16(x[k][n]); x is [K_DIM][N_DIM]
__global__ void transpose_cvt(const float* __restrict__ x,
                              unsigned short* __restrict__ xT) {
  __shared__ float tile[32][33];
  int nb = blockIdx.x * 32;
  int kb = blockIdx.y * 32;
  int tx = threadIdx.x, ty = threadIdx.y;  // (32, 8)
#pragma unroll
  for (int i = 0; i < 32; i += 8)
    tile[ty + i][tx] = x[(long)(kb + ty + i) * N_DIM + nb + tx];
  __syncthreads();
#pragma unroll
  for (int i = 0; i < 32; i += 8)
    xT[(long)(nb + ty + i) * K_DIM + kb + tx] = f2bf(tile[tx][ty + i]);
}

#define BM 128
#define BN 128
#define BK 64

// C[m][n] = bias[n] + sum_k A[m][k]*B[n][k];  A=[M][K] bf16 (W), B=[N][K] bf16 (xT)
__global__ __launch_bounds__(256) void gemm_bt_bias(
    const unsigned short* __restrict__ A,
    const unsigned short* __restrict__ B,
    const float* __restrict__ bias,
    float* __restrict__ C) {
  __shared__ unsigned short As[BM * BK];
  __shared__ unsigned short Bs[BN * BK];
  const int tid = threadIdx.x;
  const int wid = tid >> 6;
  const int lane = tid & 63;
  const int bm0 = blockIdx.y * BM;
  const int bn0 = blockIdx.x * BN;
  const int wr = wid >> 1;  // wave row (2x2 wave grid, each wave 64x64)
  const int wc = wid & 1;

  f32x4 acc[4][4] = {};

  // staging: wave w loads tile rows [w*32, w*32+32), 4 chunks of 8 rows
  // LDS dest is wave-uniform base + lane*16B: lane covers row=lane/8, col=(lane%8)*8
  const int srow = wid * 32 + (lane >> 3);
  const int scol = (lane & 7) * 8;
  const unsigned short* gA = A + (long)(bm0 + srow) * K_DIM + scol;
  const unsigned short* gB = B + (long)(bn0 + srow) * K_DIM + scol;

  const int lrow = lane & 15;
  const int lk = (lane >> 4) * 8;

  for (int k0 = 0; k0 < K_DIM; k0 += BK) {
    __syncthreads();  // prev iter's LDS reads done before overwrite
#pragma unroll
    for (int c = 0; c < 4; ++c)
      gload_lds16(gA + k0 + (long)(c * 8) * K_DIM, &As[(wid * 32 + c * 8) * BK]);
#pragma unroll
    for (int c = 0; c < 4; ++c)
      gload_lds16(gB + k0 + (long)(c * 8) * K_DIM, &Bs[(wid * 32 + c * 8) * BK]);
    __syncthreads();  // compiler emits vmcnt(0) drain before s_barrier

#pragma unroll
    for (int ks = 0; ks < 2; ++ks) {
      bf16x8 a[4], b[4];
#pragma unroll
      for (int m = 0; m < 4; ++m)
        a[m] = *(const bf16x8*)&As[(wr * 64 + m * 16 + lrow) * BK + ks * 32 + lk];
#pragma unroll
      for (int n = 0; n < 4; ++n)
        b[n] = *(const bf16x8*)&Bs[(wc * 64 + n * 16 + lrow) * BK + ks * 32 + lk];
#pragma unroll
      for (int m = 0; m < 4; ++m)
#pragma unroll
        for (int n = 0; n < 4; ++n)
          acc[m][n] = __builtin_amdgcn_mfma_f32_16x16x32_bf16(a[m], b[n], acc[m][n], 0, 0, 0);
    }
  }

  // epilogue: C/D layout col=lane&15, row=(lane>>4)*4+reg
#pragma unroll
  for (int n = 0; n < 4; ++n) {
    const int col = bn0 + wc * 64 + n * 16 + (lane & 15);
    const float bv = bias[col];
#pragma unroll
    for (int m = 0; m < 4; ++m) {
      const int row0 = bm0 + wr * 64 + m * 16 + (lane >> 4) * 4;
#pragma unroll
      for (int j = 0; j < 4; ++j)
        C[(long)(row0 + j) * N_DIM + col] = acc[m][n][j] + bv;
    }
  }
}

extern "C" void kernel_launch(void* const* d_in, const int* in_sizes, int n_in,
                              void* d_out, int out_size, void* d_ws, size_t ws_size,
                              hipStream_t stream) {
  const float* values = (const float*)d_in[0];
  const float* bias   = (const float*)d_in[1];
  const float* x      = (const float*)d_in[2];
  const int*   rows   = (const int*)d_in[3];
  const int*   cols   = (const int*)d_in[4];
  float* out = (float*)d_out;

  // ws layout: Wbf16 [M][K] (64 MiB) | xT bf16 [N][K] (32 MiB)  -> 100.7 MB total
  unsigned short* Wb = (unsigned short*)d_ws;
  unsigned short* xT = (unsigned short*)((char*)d_ws + (size_t)M_DIM * K_DIM * 2);

  // fp32 densify staging lives in d_out (exactly M*K floats); GEMM overwrites it last
  float* Wf = out;

  const long n4 = (long)M_DIM * K_DIM / 4;
  zero_f32<<<2048, 256, 0, stream>>>(Wf, n4);
  scatter_coo<<<4096, 256, 0, stream>>>(values, rows, cols, Wf);
  cvt_f32_bf16<<<4096, 256, 0, stream>>>((const float4*)Wf, (ushort4*)Wb, n4);
  transpose_cvt<<<dim3(N_DIM / 32, K_DIM / 32), dim3(32, 8), 0, stream>>>(x, xT);
  gemm_bt_bias<<<dim3(N_DIM / BN, M_DIM / BM), 256, 0, stream>>>(Wb, xT, bias, out);
}

// Round 2
// 484.466 us; speedup vs baseline: 1.3260x; 1.3260x over previous
//
#include <hip/hip_runtime.h>

#define M_DIM 8192   // IN_FEATURES (rows of W, rows of out)
#define K_DIM 4096   // OUT_FEATURES (cols of W = reduction dim)
#define N_DIM 4096   // N_COLS
#define NNZ_CNT 4194304

typedef __attribute__((ext_vector_type(8))) short bf16x8;
typedef __attribute__((ext_vector_type(4))) float f32x4;

__device__ __forceinline__ unsigned short f2bf(float f) {
  unsigned int u = __float_as_uint(f);
  unsigned int r = (u + 0x7FFFu + ((u >> 16) & 1u)) >> 16;  // RNE
  return (unsigned short)r;
}

__device__ __forceinline__ void gload_lds16(const void* g, void* l) {
  __builtin_amdgcn_global_load_lds(
      (const __attribute__((address_space(1))) void*)g,
      (__attribute__((address_space(3))) void*)l, 16, 0, 0);
}

__global__ void zero_f32(float* __restrict__ p, long n4) {
  long i = (long)blockIdx.x * blockDim.x + threadIdx.x;
  long stride = (long)gridDim.x * blockDim.x;
  float4 z = {0.f, 0.f, 0.f, 0.f};
  for (; i < n4; i += stride) ((float4*)p)[i] = z;
}

__global__ void scatter_coo(const float* __restrict__ vals,
                            const int* __restrict__ rows,
                            const int* __restrict__ cols,
                            float* __restrict__ W) {
  int i = blockIdx.x * blockDim.x + threadIdx.x;
  int stride = gridDim.x * blockDim.x;
  for (; i < NNZ_CNT; i += stride)
    atomicAdd(&W[(long)rows[i] * K_DIM + cols[i]], vals[i]);
}

__global__ void cvt_f32_bf16(const float4* __restrict__ src,
                             ushort4* __restrict__ dst, long n4) {
  long i = (long)blockIdx.x * blockDim.x + threadIdx.x;
  long stride = (long)gridDim.x * blockDim.x;
  for (; i < n4; i += stride) {
    float4 v = src[i];
    ushort4 o;
    o.x = f2bf(v.x); o.y = f2bf(v.y); o.z = f2bf(v.z); o.w = f2bf(v.w);
    dst[i] = o;
  }
}

// xT[n][k] = bf16(x[k][n]); x is [K_DIM][N_DIM]
__global__ void transpose_cvt(const float* __restrict__ x,
                              unsigned short* __restrict__ xT) {
  __shared__ float tile[32][33];
  int nb = blockIdx.x * 32;
  int kb = blockIdx.y * 32;
  int tx = threadIdx.x, ty = threadIdx.y;  // (32, 8)
#pragma unroll
  for (int i = 0; i < 32; i += 8)
    tile[ty + i][tx] = x[(long)(kb + ty + i) * N_DIM + nb + tx];
  __syncthreads();
#pragma unroll
  for (int i = 0; i < 32; i += 8)
    xT[(long)(nb + ty + i) * K_DIM + kb + tx] = f2bf(tile[tx][ty + i]);
}

// ================== 256x256 / BK=64 8-phase bf16 GEMM ==================
// C[m][n] = bias[n] + sum_k A[m][k]*B[n][k];  A=[M][K] (W bf16), B=[N][K] (xT)
// LDS per buffer: A tile 256x64 bf16 (32 KB, 128B rows, XOR-swizzled) + B same.
// Double-buffered -> 128 KB dynamic LDS. 8 waves: wr=wid>>2 (2), wc=wid&3 (4);
// wave output 128x64 -> acc[8][4] f32x4.
// Swizzle: phys_colbyte = logical_colbyte ^ ((row&7)<<4).  global_load_lds
// writes LINEAR phys; the global SOURCE column is inverse-swizzled per thread
// (involution), ds_reads apply the same XOR -> 2-way bank aliasing (free).
// Stage schedule per K-tile u (reads: P1 A(m0-3)+B(n0-1), P2 B(n2-3), P3 A(m4-7)):
//   P1: A-half0(u+1)  P2: A-half1(u+1)   (other buffer; A region free since u-1)
//   P3: B-half0(u+2)  P4: B-half1(u+2)   (current buffer; B reads done end-P2)
// vmcnt(4) once per tile at P4 -> 2 half-tiles in flight; last 2 tiles drain 0.

#define LDS_BUF   65536
#define LDS_B_OFF 32768

template<bool STA, bool STB, bool FIN>
__device__ __forceinline__ void tile_body(
    int u, int cur,
    const unsigned short* __restrict__ Ag, const unsigned short* __restrict__ Bg,
    char* smem, int st16,
    int a_off0, int a_off1, int b_off0, int b_off1,
    bf16x8 (&a)[4][2], bf16x8 (&b)[4][2], f32x4 (&acc)[8][4]) {
  char* Acur = smem + cur * LDS_BUF;
  char* Bcur = Acur + LDS_B_OFF;
  char* Aoth = smem + (cur ^ 1) * LDS_BUF;
  const unsigned short* Asrc = Ag + (long)(u + 1) * 64;
  const unsigned short* Bsrc = Bg + (long)(u + 2) * 64;

  // -------- phase 1: ds_read A(m0-3)x2 + B(n0-1)x2 (12 reads); stage A-half0
#pragma unroll
  for (int m = 0; m < 4; ++m) {
    a[m][0] = *(const bf16x8*)(Acur + m * 2048 + a_off0);
    a[m][1] = *(const bf16x8*)(Acur + m * 2048 + a_off1);
  }
#pragma unroll
  for (int n = 0; n < 2; ++n) {
    b[n][0] = *(const bf16x8*)(Bcur + n * 2048 + b_off0);
    b[n][1] = *(const bf16x8*)(Bcur + n * 2048 + b_off1);
  }
  if (STA) {
    gload_lds16(Asrc, Aoth + st16);
    gload_lds16(Asrc + (long)64 * K_DIM, Aoth + 8192 + st16);
  }
  __builtin_amdgcn_s_barrier();
  asm volatile("s_waitcnt lgkmcnt(0)" ::: "memory");
  __builtin_amdgcn_sched_barrier(0);
  __builtin_amdgcn_s_setprio(1);
#pragma unroll
  for (int m = 0; m < 4; ++m)
#pragma unroll
    for (int n = 0; n < 2; ++n) {
      acc[m][n] = __builtin_amdgcn_mfma_f32_16x16x32_bf16(a[m][0], b[n][0], acc[m][n], 0, 0, 0);
      acc[m][n] = __builtin_amdgcn_mfma_f32_16x16x32_bf16(a[m][1], b[n][1], acc[m][n], 0, 0, 0);
    }
  __builtin_amdgcn_s_setprio(0);
  __builtin_amdgcn_s_barrier();

  // -------- phase 2: ds_read B(n2-3) (4 reads); stage A-half1
#pragma unroll
  for (int n = 2; n < 4; ++n) {
    b[n][0] = *(const bf16x8*)(Bcur + n * 2048 + b_off0);
    b[n][1] = *(const bf16x8*)(Bcur + n * 2048 + b_off1);
  }
  if (STA) {
    gload_lds16(Asrc + (long)128 * K_DIM, Aoth + 16384 + st16);
    gload_lds16(Asrc + (long)192 * K_DIM, Aoth + 24576 + st16);
  }
  __builtin_amdgcn_s_barrier();
  asm volatile("s_waitcnt lgkmcnt(0)" ::: "memory");
  __builtin_amdgcn_sched_barrier(0);
  __builtin_amdgcn_s_setprio(1);
#pragma unroll
  for (int m = 0; m < 4; ++m)
#pragma unroll
    for (int n = 2; n < 4; ++n) {
      acc[m][n] = __builtin_amdgcn_mfma_f32_16x16x32_bf16(a[m][0], b[n][0], acc[m][n], 0, 0, 0);
      acc[m][n] = __builtin_amdgcn_mfma_f32_16x16x32_bf16(a[m][1], b[n][1], acc[m][n], 0, 0, 0);
    }
  __builtin_amdgcn_s_setprio(0);
  __builtin_amdgcn_s_barrier();

  // -------- phase 3: ds_read A(m4-7) (8 reads, reuse regs); stage B-half0(u+2)
#pragma unroll
  for (int m = 0; m < 4; ++m) {
    a[m][0] = *(const bf16x8*)(Acur + (m + 4) * 2048 + a_off0);
    a[m][1] = *(const bf16x8*)(Acur + (m + 4) * 2048 + a_off1);
  }
  if (STB) {
    gload_lds16(Bsrc, Bcur + st16);
    gload_lds16(Bsrc + (long)64 * K_DIM, Bcur + 8192 + st16);
  }
  __builtin_amdgcn_s_barrier();
  asm volatile("s_waitcnt lgkmcnt(0)" ::: "memory");
  __builtin_amdgcn_sched_barrier(0);
  __builtin_amdgcn_s_setprio(1);
#pragma unroll
  for (int m = 0; m < 4; ++m)
#pragma unroll
    for (int n = 0; n < 2; ++n) {
      acc[m + 4][n] = __builtin_amdgcn_mfma_f32_16x16x32_bf16(a[m][0], b[n][0], acc[m + 4][n], 0, 0, 0);
      acc[m + 4][n] = __builtin_amdgcn_mfma_f32_16x16x32_bf16(a[m][1], b[n][1], acc[m + 4][n], 0, 0, 0);
    }
  __builtin_amdgcn_s_setprio(0);
  __builtin_amdgcn_s_barrier();

  // -------- phase 4: no ds_read; stage B-half1(u+2); counted vmcnt
  if (STB) {
    gload_lds16(Bsrc + (long)128 * K_DIM, Bcur + 16384 + st16);
    gload_lds16(Bsrc + (long)192 * K_DIM, Bcur + 24576 + st16);
  }
  if (FIN) asm volatile("s_waitcnt vmcnt(0)" ::: "memory");
  else     asm volatile("s_waitcnt vmcnt(4)" ::: "memory");
  __builtin_amdgcn_s_barrier();
  __builtin_amdgcn_s_setprio(1);
#pragma unroll
  for (int m = 0; m < 4; ++m)
#pragma unroll
    for (int n = 2; n < 4; ++n) {
      acc[m + 4][n] = __builtin_amdgcn_mfma_f32_16x16x32_bf16(a[m][0], b[n][0], acc[m + 4][n], 0, 0, 0);
      acc[m + 4][n] = __builtin_amdgcn_mfma_f32_16x16x32_bf16(a[m][1], b[n][1], acc[m + 4][n], 0, 0, 0);
    }
  __builtin_amdgcn_s_setprio(0);
  __builtin_amdgcn_s_barrier();
}

__global__ __launch_bounds__(512, 2) void gemm8(
    const unsigned short* __restrict__ A,
    const unsigned short* __restrict__ B,
    const float* __restrict__ bias,
    float* __restrict__ C) {
  extern __shared__ __align__(16) char smem[];
  const int tid = threadIdx.x;
  const int lane = tid & 63;
  const int wid = tid >> 6;
  const int wr = wid >> 2, wc = wid & 3;
  const int bm0 = blockIdx.y * 256, bn0 = blockIdx.x * 256;

  // staging source mapping (inverse-swizzled global column, linear LDS dest)
  const int srow = tid >> 3;                          // 0..63
  const int pcb = (tid & 7) << 4;                     // phys col-byte
  const int scol = (pcb ^ ((srow & 7) << 4)) >> 1;    // logical col (elements)
  const unsigned short* Ag = A + (long)(bm0 + srow) * K_DIM + scol;
  const unsigned short* Bg = B + (long)(bn0 + srow) * K_DIM + scol;
  const int st16 = tid * 16;

  // fragment read offsets (swizzled) within a 256x64 tile (128B rows)
  const int q = (lane >> 4) << 4;
  const int s = (lane & 7) << 4;
  const int qs = q ^ s;
  const int a_off0 = (wr * 128 + (lane & 15)) * 128 + qs;
  const int a_off1 = a_off0 ^ 64;
  const int b_off0 = (wc * 64 + (lane & 15)) * 128 + qs;
  const int b_off1 = b_off0 ^ 64;

  f32x4 acc[8][4] = {};
  bf16x8 a[4][2], b[4][2];

  // prologue: stage full tile 0 (buf0) first, then B halves of tile 1 (buf1)
#pragma unroll
  for (int h = 0; h < 2; ++h)
#pragma unroll
    for (int r = 0; r < 2; ++r) {
      gload_lds16(Ag + (long)(h * 128 + r * 64) * K_DIM,
                  smem + h * 16384 + r * 8192 + st16);
      gload_lds16(Bg + (long)(h * 128 + r * 64) * K_DIM,
                  smem + LDS_B_OFF + h * 16384 + r * 8192 + st16);
    }
#pragma unroll
  for (int h = 0; h < 2; ++h)
#pragma unroll
    for (int r = 0; r < 2; ++r)
      gload_lds16(Bg + (long)(h * 128 + r * 64) * K_DIM + 64,
                  smem + LDS_BUF + LDS_B_OFF + h * 16384 + r * 8192 + st16);
  asm volatile("s_waitcnt vmcnt(4)" ::: "memory");
  __builtin_amdgcn_s_barrier();

  // main loop: tiles 0..61 fully pipelined; peel 62 (drain) and 63
#pragma unroll 1
  for (int u2 = 0; u2 < 31; ++u2) {
    tile_body<true, true, false>(2 * u2, 0, Ag, Bg, smem, st16,
                                 a_off0, a_off1, b_off0, b_off1, a, b, acc);
    tile_body<true, true, false>(2 * u2 + 1, 1, Ag, Bg, smem, st16,
                                 a_off0, a_off1, b_off0, b_off1, a, b, acc);
  }
  tile_body<true, false, true>(62, 0, Ag, Bg, smem, st16,
                               a_off0, a_off1, b_off0, b_off1, a, b, acc);
  tile_body<false, false, true>(63, 1, Ag, Bg, smem, st16,
                                a_off0, a_off1, b_off0, b_off1, a, b, acc);

  // epilogue: C/D layout col=lane&15, row=(lane>>4)*4+reg
#pragma unroll
  for (int n = 0; n < 4; ++n) {
    const int col = bn0 + wc * 64 + n * 16 + (lane & 15);
    const float bv = bias[col];
#pragma unroll
    for (int m = 0; m < 8; ++m) {
      const int r0 = bm0 + wr * 128 + m * 16 + (lane >> 4) * 4;
#pragma unroll
      for (int j = 0; j < 4; ++j)
        C[(long)(r0 + j) * N_DIM + col] = acc[m][n][j] + bv;
    }
  }
}

extern "C" void kernel_launch(void* const* d_in, const int* in_sizes, int n_in,
                              void* d_out, int out_size, void* d_ws, size_t ws_size,
                              hipStream_t stream) {
  const float* values = (const float*)d_in[0];
  const float* bias   = (const float*)d_in[1];
  const float* x      = (const float*)d_in[2];
  const int*   rows   = (const int*)d_in[3];
  const int*   cols   = (const int*)d_in[4];
  float* out = (float*)d_out;

  // ws layout: Wbf16 [M][K] (64 MiB) | xT bf16 [N][K] (32 MiB)
  unsigned short* Wb = (unsigned short*)d_ws;
  unsigned short* xT = (unsigned short*)((char*)d_ws + (size_t)M_DIM * K_DIM * 2);

  // fp32 densify staging lives in d_out (exactly M*K floats); GEMM overwrites it
  float* Wf = out;

  hipFuncSetAttribute((const void*)gemm8,
                      hipFuncAttributeMaxDynamicSharedMemorySize, 131072);

  const long n4 = (long)M_DIM * K_DIM / 4;
  zero_f32<<<2048, 256, 0, stream>>>(Wf, n4);
  scatter_coo<<<4096, 256, 0, stream>>>(values, rows, cols, Wf);
  cvt_f32_bf16<<<4096, 256, 0, stream>>>((const float4*)Wf, (ushort4*)Wb, n4);
  transpose_cvt<<<dim3(N_DIM / 32, K_DIM / 32), dim3(32, 8), 0, stream>>>(x, xT);
  gemm8<<<dim3(N_DIM / 256, M_DIM / 256), 512, 131072, stream>>>(Wb, xT, bias, out);
}

// Round 3
// 447.560 us; speedup vs baseline: 1.4353x; 1.0825x over previous
//
#include <hip/hip_runtime.h>

#define M_DIM 8192   // IN_FEATURES (rows of W, rows of out)
#define K_DIM 4096   // OUT_FEATURES (cols of W = reduction dim)
#define N_DIM 4096   // N_COLS
#define NNZ_CNT 4194304
#define GRID_X 16    // N_DIM/256
#define GRID_Y 32    // M_DIM/256

typedef __attribute__((ext_vector_type(8))) short bf16x8;
typedef __attribute__((ext_vector_type(4))) float f32x4;

__device__ __forceinline__ unsigned short f2bf(float f) {
  unsigned int u = __float_as_uint(f);
  unsigned int r = (u + 0x7FFFu + ((u >> 16) & 1u)) >> 16;  // RNE
  return (unsigned short)r;
}

__device__ __forceinline__ void gload_lds16(const void* g, void* l) {
  __builtin_amdgcn_global_load_lds(
      (const __attribute__((address_space(1))) void*)g,
      (__attribute__((address_space(3))) void*)l, 16, 0, 0);
}

__global__ void zero_f32(float* __restrict__ p, long n4) {
  long i = (long)blockIdx.x * blockDim.x + threadIdx.x;
  long stride = (long)gridDim.x * blockDim.x;
  float4 z = {0.f, 0.f, 0.f, 0.f};
  for (; i < n4; i += stride) ((float4*)p)[i] = z;
}

// Scatter COO directly into bf16 W via packed-bf16 atomic add.
// Pair-aligned: the untouched half adds +0.0 (identity). Duplicates (~260k
// cells) accumulate in bf16; extra rounding error << bf16-GEMM error budget.
__global__ void scatter_pk(const float* __restrict__ vals,
                           const int* __restrict__ rows,
                           const int* __restrict__ cols,
                           unsigned int* __restrict__ Wb2) {
  int i = blockIdx.x * blockDim.x + threadIdx.x;
  int stride = gridDim.x * blockDim.x;
  for (; i < NNZ_CNT; i += stride) {
    int r = rows[i], c = cols[i];
    unsigned int bv = f2bf(vals[i]);
    unsigned int pk = (c & 1) ? (bv << 16) : bv;
    unsigned long long addr =
        (unsigned long long)(Wb2 + (((long)r * K_DIM + c) >> 1));
    asm volatile("global_atomic_pk_add_bf16 %0, %1, off"
                 :: "v"(addr), "v"(pk) : "memory");
  }
}

// xT[n][k] = bf16(x[k][n]); x is [K_DIM][N_DIM]
__global__ void transpose_cvt(const float* __restrict__ x,
                              unsigned short* __restrict__ xT) {
  __shared__ float tile[32][33];
  int nb = blockIdx.x * 32;
  int kb = blockIdx.y * 32;
  int tx = threadIdx.x, ty = threadIdx.y;  // (32, 8)
#pragma unroll
  for (int i = 0; i < 32; i += 8)
    tile[ty + i][tx] = x[(long)(kb + ty + i) * N_DIM + nb + tx];
  __syncthreads();
#pragma unroll
  for (int i = 0; i < 32; i += 8)
    xT[(long)(nb + ty + i) * K_DIM + kb + tx] = f2bf(tile[tx][ty + i]);
}

// ================== 256x256 / BK=64 8-phase bf16 GEMM ==================
// C[m][n] = bias[n] + sum_k A[m][k]*B[n][k];  A=[M][K] (W bf16), B=[N][K] (xT)
// 128 KB double-buffered LDS, 8 waves (2x4), st_16x32-style XOR swizzle
// (inverse-swizzled global source + swizzled ds_read; LDS dest linear).
// Counted vmcnt(4) once per K-tile; XCD-aware bijective block swizzle.

#define LDS_BUF   65536
#define LDS_B_OFF 32768

template<bool STA, bool STB, bool FIN>
__device__ __forceinline__ void tile_body(
    int u, int cur,
    const unsigned short* __restrict__ Ag, const unsigned short* __restrict__ Bg,
    char* smem, int st16,
    int a_off0, int a_off1, int b_off0, int b_off1,
    bf16x8 (&a)[4][2], bf16x8 (&b)[4][2], f32x4 (&acc)[8][4]) {
  char* Acur = smem + cur * LDS_BUF;
  char* Bcur = Acur + LDS_B_OFF;
  char* Aoth = smem + (cur ^ 1) * LDS_BUF;
  const unsigned short* Asrc = Ag + (long)(u + 1) * 64;
  const unsigned short* Bsrc = Bg + (long)(u + 2) * 64;

  // -------- phase 1: ds_read A(m0-3)x2 + B(n0-1)x2 (12 reads); stage A-half0
#pragma unroll
  for (int m = 0; m < 4; ++m) {
    a[m][0] = *(const bf16x8*)(Acur + m * 2048 + a_off0);
    a[m][1] = *(const bf16x8*)(Acur + m * 2048 + a_off1);
  }
#pragma unroll
  for (int n = 0; n < 2; ++n) {
    b[n][0] = *(const bf16x8*)(Bcur + n * 2048 + b_off0);
    b[n][1] = *(const bf16x8*)(Bcur + n * 2048 + b_off1);
  }
  if (STA) {
    gload_lds16(Asrc, Aoth + st16);
    gload_lds16(Asrc + (long)64 * K_DIM, Aoth + 8192 + st16);
  }
  __builtin_amdgcn_s_barrier();
  asm volatile("s_waitcnt lgkmcnt(0)" ::: "memory");
  __builtin_amdgcn_sched_barrier(0);
  __builtin_amdgcn_s_setprio(1);
#pragma unroll
  for (int m = 0; m < 4; ++m)
#pragma unroll
    for (int n = 0; n < 2; ++n) {
      acc[m][n] = __builtin_amdgcn_mfma_f32_16x16x32_bf16(a[m][0], b[n][0], acc[m][n], 0, 0, 0);
      acc[m][n] = __builtin_amdgcn_mfma_f32_16x16x32_bf16(a[m][1], b[n][1], acc[m][n], 0, 0, 0);
    }
  __builtin_amdgcn_s_setprio(0);
  __builtin_amdgcn_s_barrier();

  // -------- phase 2: ds_read B(n2-3) (4 reads); stage A-half1
#pragma unroll
  for (int n = 2; n < 4; ++n) {
    b[n][0] = *(const bf16x8*)(Bcur + n * 2048 + b_off0);
    b[n][1] = *(const bf16x8*)(Bcur + n * 2048 + b_off1);
  }
  if (STA) {
    gload_lds16(Asrc + (long)128 * K_DIM, Aoth + 16384 + st16);
    gload_lds16(Asrc + (long)192 * K_DIM, Aoth + 24576 + st16);
  }
  __builtin_amdgcn_s_barrier();
  asm volatile("s_waitcnt lgkmcnt(0)" ::: "memory");
  __builtin_amdgcn_sched_barrier(0);
  __builtin_amdgcn_s_setprio(1);
#pragma unroll
  for (int m = 0; m < 4; ++m)
#pragma unroll
    for (int n = 2; n < 4; ++n) {
      acc[m][n] = __builtin_amdgcn_mfma_f32_16x16x32_bf16(a[m][0], b[n][0], acc[m][n], 0, 0, 0);
      acc[m][n] = __builtin_amdgcn_mfma_f32_16x16x32_bf16(a[m][1], b[n][1], acc[m][n], 0, 0, 0);
    }
  __builtin_amdgcn_s_setprio(0);
  __builtin_amdgcn_s_barrier();

  // -------- phase 3: ds_read A(m4-7) (8 reads, reuse regs); stage B-half0(u+2)
#pragma unroll
  for (int m = 0; m < 4; ++m) {
    a[m][0] = *(const bf16x8*)(Acur + (m + 4) * 2048 + a_off0);
    a[m][1] = *(const bf16x8*)(Acur + (m + 4) * 2048 + a_off1);
  }
  if (STB) {
    gload_lds16(Bsrc, Bcur + st16);
    gload_lds16(Bsrc + (long)64 * K_DIM, Bcur + 8192 + st16);
  }
  __builtin_amdgcn_s_barrier();
  asm volatile("s_waitcnt lgkmcnt(0)" ::: "memory");
  __builtin_amdgcn_sched_barrier(0);
  __builtin_amdgcn_s_setprio(1);
#pragma unroll
  for (int m = 0; m < 4; ++m)
#pragma unroll
    for (int n = 0; n < 2; ++n) {
      acc[m + 4][n] = __builtin_amdgcn_mfma_f32_16x16x32_bf16(a[m][0], b[n][0], acc[m + 4][n], 0, 0, 0);
      acc[m + 4][n] = __builtin_amdgcn_mfma_f32_16x16x32_bf16(a[m][1], b[n][1], acc[m + 4][n], 0, 0, 0);
    }
  __builtin_amdgcn_s_setprio(0);
  __builtin_amdgcn_s_barrier();

  // -------- phase 4: no ds_read; stage B-half1(u+2); counted vmcnt
  if (STB) {
    gload_lds16(Bsrc + (long)128 * K_DIM, Bcur + 16384 + st16);
    gload_lds16(Bsrc + (long)192 * K_DIM, Bcur + 24576 + st16);
  }
  if (FIN) asm volatile("s_waitcnt vmcnt(0)" ::: "memory");
  else     asm volatile("s_waitcnt vmcnt(4)" ::: "memory");
  __builtin_amdgcn_s_barrier();
  __builtin_amdgcn_s_setprio(1);
#pragma unroll
  for (int m = 0; m < 4; ++m)
#pragma unroll
    for (int n = 2; n < 4; ++n) {
      acc[m + 4][n] = __builtin_amdgcn_mfma_f32_16x16x32_bf16(a[m][0], b[n][0], acc[m + 4][n], 0, 0, 0);
      acc[m + 4][n] = __builtin_amdgcn_mfma_f32_16x16x32_bf16(a[m][1], b[n][1], acc[m + 4][n], 0, 0, 0);
    }
  __builtin_amdgcn_s_setprio(0);
  __builtin_amdgcn_s_barrier();
}

__global__ __launch_bounds__(512, 2) void gemm8(
    const unsigned short* __restrict__ A,
    const unsigned short* __restrict__ B,
    const float* __restrict__ bias,
    float* __restrict__ C) {
  extern __shared__ __align__(16) char smem[];
  const int tid = threadIdx.x;
  const int lane = tid & 63;
  const int wid = tid >> 6;
  const int wr = wid >> 2, wc = wid & 3;

  // XCD-aware bijective swizzle: nwg=512, 512%8==0 -> each XCD gets a
  // contiguous chunk of 64 tiles (4 rows x 16 cols) for L2 panel reuse.
  const int wg0 = blockIdx.y * GRID_X + blockIdx.x;
  const int swz = (wg0 & 7) * (GRID_X * GRID_Y / 8) + (wg0 >> 3);
  const int bm0 = (swz >> 4) * 256;   // swz / GRID_X
  const int bn0 = (swz & 15) * 256;   // swz % GRID_X

  // staging source mapping (inverse-swizzled global column, linear LDS dest)
  const int srow = tid >> 3;                          // 0..63
  const int pcb = (tid & 7) << 4;                     // phys col-byte
  const int scol = (pcb ^ ((srow & 7) << 4)) >> 1;    // logical col (elements)
  const unsigned short* Ag = A + (long)(bm0 + srow) * K_DIM + scol;
  const unsigned short* Bg = B + (long)(bn0 + srow) * K_DIM + scol;
  const int st16 = tid * 16;

  // fragment read offsets (swizzled) within a 256x64 tile (128B rows)
  const int q = (lane >> 4) << 4;
  const int s = (lane & 7) << 4;
  const int qs = q ^ s;
  const int a_off0 = (wr * 128 + (lane & 15)) * 128 + qs;
  const int a_off1 = a_off0 ^ 64;
  const int b_off0 = (wc * 64 + (lane & 15)) * 128 + qs;
  const int b_off1 = b_off0 ^ 64;

  f32x4 acc[8][4] = {};
  bf16x8 a[4][2], b[4][2];

  // prologue: stage full tile 0 (buf0) first, then B halves of tile 1 (buf1)
#pragma unroll
  for (int h = 0; h < 2; ++h)
#pragma unroll
    for (int r = 0; r < 2; ++r) {
      gload_lds16(Ag + (long)(h * 128 + r * 64) * K_DIM,
                  smem + h * 16384 + r * 8192 + st16);
      gload_lds16(Bg + (long)(h * 128 + r * 64) * K_DIM,
                  smem + LDS_B_OFF + h * 16384 + r * 8192 + st16);
    }
#pragma unroll
  for (int h = 0; h < 2; ++h)
#pragma unroll
    for (int r = 0; r < 2; ++r)
      gload_lds16(Bg + (long)(h * 128 + r * 64) * K_DIM + 64,
                  smem + LDS_BUF + LDS_B_OFF + h * 16384 + r * 8192 + st16);
  asm volatile("s_waitcnt vmcnt(4)" ::: "memory");
  __builtin_amdgcn_s_barrier();

  // main loop: tiles 0..61 fully pipelined; peel 62 (drain) and 63
#pragma unroll 1
  for (int u2 = 0; u2 < 31; ++u2) {
    tile_body<true, true, false>(2 * u2, 0, Ag, Bg, smem, st16,
                                 a_off0, a_off1, b_off0, b_off1, a, b, acc);
    tile_body<true, true, false>(2 * u2 + 1, 1, Ag, Bg, smem, st16,
                                 a_off0, a_off1, b_off0, b_off1, a, b, acc);
  }
  tile_body<true, false, true>(62, 0, Ag, Bg, smem, st16,
                               a_off0, a_off1, b_off0, b_off1, a, b, acc);
  tile_body<false, false, true>(63, 1, Ag, Bg, smem, st16,
                                a_off0, a_off1, b_off0, b_off1, a, b, acc);

  // epilogue: C/D layout col=lane&15, row=(lane>>4)*4+reg
#pragma unroll
  for (int n = 0; n < 4; ++n) {
    const int col = bn0 + wc * 64 + n * 16 + (lane & 15);
    const float bv = bias[col];
#pragma unroll
    for (int m = 0; m < 8; ++m) {
      const int r0 = bm0 + wr * 128 + m * 16 + (lane >> 4) * 4;
#pragma unroll
      for (int j = 0; j < 4; ++j)
        C[(long)(r0 + j) * N_DIM + col] = acc[m][n][j] + bv;
    }
  }
}

extern "C" void kernel_launch(void* const* d_in, const int* in_sizes, int n_in,
                              void* d_out, int out_size, void* d_ws, size_t ws_size,
                              hipStream_t stream) {
  const float* values = (const float*)d_in[0];
  const float* bias   = (const float*)d_in[1];
  const float* x      = (const float*)d_in[2];
  const int*   rows   = (const int*)d_in[3];
  const int*   cols   = (const int*)d_in[4];
  float* out = (float*)d_out;

  // ws layout: Wbf16 [M][K] (64 MiB) | xT bf16 [N][K] (32 MiB)
  unsigned short* Wb = (unsigned short*)d_ws;
  unsigned short* xT = (unsigned short*)((char*)d_ws + (size_t)M_DIM * K_DIM * 2);

  hipFuncSetAttribute((const void*)gemm8,
                      hipFuncAttributeMaxDynamicSharedMemorySize, 131072);

  // zero bf16 W (64 MB), scatter bf16 atomics, transpose+cvt x, GEMM
  const long nz4 = (long)M_DIM * K_DIM * 2 / 16;  // float4 count over 64 MB
  zero_f32<<<2048, 256, 0, stream>>>((float*)Wb, nz4);
  scatter_pk<<<4096, 256, 0, stream>>>(values, rows, cols, (unsigned int*)Wb);
  transpose_cvt<<<dim3(N_DIM / 32, K_DIM / 32), dim3(32, 8), 0, stream>>>(x, xT);
  gemm8<<<dim3(GRID_X, GRID_Y), 512, 131072, stream>>>(Wb, xT, bias, out);
}